// Round 5
// baseline (208.138 us; speedup 1.0000x reference)
//
#include <hip/hip_runtime.h>
#include <hip/hip_fp16.h>

#define NN   100000
#define EE   1250000
#define DIN  128
#define HID  64
#define DOUT 40

#define BN   512                  // nodes per bucket
#define NB   196                  // ceil(NN/BN)
#define CH   4096                 // edges per scatter block (16/thread)
#define SEG  8192                 // padded bucket capacity (mean 6377, 22 sigma)
#define S_BLKS 306                // ceil(EE/CH)
#define G_BLKS 1563               // ceil(NN/64)

typedef _Float16 v8h __attribute__((ext_vector_type(8)));
typedef float    v4f __attribute__((ext_vector_type(4)));

// unpack a float4-of-8-halves and accumulate into 2 float4s
__device__ __forceinline__ void acc8(const float4& v, float4& lo, float4& hi) {
    const __half2* hp = (const __half2*)&v;
    float2 f0 = __half22float2(hp[0]), f1 = __half22float2(hp[1]);
    float2 f2 = __half22float2(hp[2]), f3 = __half22float2(hp[3]);
    lo.x += f0.x; lo.y += f0.y; lo.z += f1.x; lo.w += f1.y;
    hi.x += f2.x; hi.y += f2.y; hi.z += f3.x; hi.w += f3.y;
}

// predicated/scaled accumulate: acc += v * s
__device__ __forceinline__ void fma8(const float4& v, float s, float4& lo, float4& hi) {
    const __half2* hp = (const __half2*)&v;
    float2 f0 = __half22float2(hp[0]), f1 = __half22float2(hp[1]);
    float2 f2 = __half22float2(hp[2]), f3 = __half22float2(hp[3]);
    lo.x += f0.x * s; lo.y += f0.y * s; lo.z += f1.x * s; lo.w += f1.y * s;
    hi.x += f2.x * s; hi.y += f2.y * s; hi.z += f3.x * s; hi.w += f3.y * s;
}

// scale by d, convert to 8 halves, store 16B
__device__ __forceinline__ void sthalf8(__half* p, const float4& lo, const float4& hi, float d) {
    float4 st;
    __half2* hp = (__half2*)&st;
    hp[0] = __floats2half2_rn(lo.x * d, lo.y * d);
    hp[1] = __floats2half2_rn(lo.z * d, lo.w * d);
    hp[2] = __floats2half2_rn(hi.x * d, hi.y * d);
    hp[3] = __floats2half2_rn(hi.z * d, hi.w * d);
    *(float4*)p = st;
}

// ---- software-pipelined gather helpers ----
__device__ __forceinline__ void load8(const int* __restrict__ esrc, int base, int* e) {
#pragma unroll
    for (int u = 0; u < 8; ++u) e[u] = esrc[base + u];
}

// layer-1: gathers + per-src dinv + sel bits
__device__ __forceinline__ void gath8d(const float4* __restrict__ tab4,
                                       const float* __restrict__ dinv,
                                       const int* e, int q, float4* v, float* dv, int& s) {
#pragma unroll
    for (int u = 0; u < 8; ++u) {
        int id = e[u] & 0x1FFFF;
        v[u] = tab4[(size_t)id * 8 + q];
        dv[u] = dinv[id];
    }
    s = 0;
#pragma unroll
    for (int u = 0; u < 8; ++u) s |= ((e[u] >> 17) & 1) << u;
}

__device__ __forceinline__ void unp8d(const float4* v, const float* dv, int s,
                                      float4& tl, float4& th, float4& bl, float4& bh) {
#pragma unroll
    for (int u = 0; u < 8; ++u) {
        float d = dv[u];
        float ds = ((s >> u) & 1) ? d : 0.f;
        fma8(v[u], d, tl, th);
        fma8(v[u], ds, bl, bh);
    }
}

// layer-2 (packed 80B rows, pre-scaled table): gathers + sel bits
__device__ __forceinline__ void gath8p(const float4* __restrict__ tab4,
                                       const int* e, int qc, float4* v, int& s) {
#pragma unroll
    for (int u = 0; u < 8; ++u) v[u] = tab4[(size_t)(e[u] & 0x1FFFF) * 5 + qc];
    s = 0;
#pragma unroll
    for (int u = 0; u < 8; ++u) s |= ((e[u] >> 17) & 1) << u;
}

__device__ __forceinline__ void unp8(const float4* v, int s,
                                     float4& tl, float4& th, float4& bl, float4& bh) {
#pragma unroll
    for (int u = 0; u < 8; ++u) {
        float su = (float)((s >> u) & 1);
        acc8(v[u], tl, th);
        fma8(v[u], su, bl, bh);
    }
}

// 2-deep ping-pong pipelined aggregation, layer-1 (unscaled table, per-edge dinv)
__device__ __forceinline__ void agg_span1(const float4* __restrict__ tab4,
                                          const float* __restrict__ dinv,
                                          const int* __restrict__ esrc,
                                          int j, int je, int q,
                                          float4& tl, float4& th, float4& bl, float4& bh) {
    int eA[8], eB[8];
    float4 vA[8], vB[8];
    float dA[8], dB[8];
    int sA, sB;
    int n8 = (je - j) >> 3;
    if (n8 > 0) {
        int lastb = j + (n8 - 1) * 8;
        load8(esrc, j, eA);
        gath8d(tab4, dinv, eA, q, vA, dA, sA);
        if (n8 == 1) {
            unp8d(vA, dA, sA, tl, th, bl, bh);
        } else {
            load8(esrc, j + 8, eB);
            int m = 1;
            while (true) {
                load8(esrc, min(j + (m + 1) * 8, lastb), eA);
                gath8d(tab4, dinv, eB, q, vB, dB, sB);
                unp8d(vA, dA, sA, tl, th, bl, bh);
                ++m;
                if (m >= n8) { unp8d(vB, dB, sB, tl, th, bl, bh); break; }
                load8(esrc, min(j + (m + 1) * 8, lastb), eB);
                gath8d(tab4, dinv, eA, q, vA, dA, sA);
                unp8d(vB, dB, sB, tl, th, bl, bh);
                ++m;
                if (m >= n8) { unp8d(vA, dA, sA, tl, th, bl, bh); break; }
            }
        }
        j += n8 << 3;
    }
    for (; j < je; ++j) {
        int e = esrc[j];
        int id = e & 0x1FFFF;
        float4 v = tab4[(size_t)id * 8 + q];
        float d = dinv[id];
        float ds = ((e >> 17) & 1) ? d : 0.f;
        fma8(v, d, tl, th);
        fma8(v, ds, bl, bh);
    }
}

// 2-deep ping-pong pipelined aggregation, layer-2 (packed pre-scaled table)
__device__ __forceinline__ void agg_span2(const float4* __restrict__ tab4,
                                          const int* __restrict__ esrc,
                                          int j, int je, int qc,
                                          float4& tl, float4& th, float4& bl, float4& bh) {
    int eA[8], eB[8];
    float4 vA[8], vB[8];
    int sA, sB;
    int n8 = (je - j) >> 3;
    if (n8 > 0) {
        int lastb = j + (n8 - 1) * 8;
        load8(esrc, j, eA);
        gath8p(tab4, eA, qc, vA, sA);
        if (n8 == 1) {
            unp8(vA, sA, tl, th, bl, bh);
        } else {
            load8(esrc, j + 8, eB);
            int m = 1;
            while (true) {
                load8(esrc, min(j + (m + 1) * 8, lastb), eA);
                gath8p(tab4, eB, qc, vB, sB);
                unp8(vA, sA, tl, th, bl, bh);
                ++m;
                if (m >= n8) { unp8(vB, sB, tl, th, bl, bh); break; }
                load8(esrc, min(j + (m + 1) * 8, lastb), eB);
                gath8p(tab4, eA, qc, vA, sA);
                unp8(vB, sB, tl, th, bl, bh);
                ++m;
                if (m >= n8) { unp8(vA, sA, tl, th, bl, bh); break; }
            }
        }
        j += n8 << 3;
    }
    for (; j < je; ++j) {
        int e = esrc[j];
        float4 v = tab4[(size_t)(e & 0x1FFFF) * 5 + qc];
        float su = (float)((e >> 17) & 1);
        acc8(v, tl, th);
        fma8(v, su, bl, bh);
    }
}

// ---------------- W1 & W2 -> B-fragment pre-pack + bucket_fill zero ----------------
__global__ __launch_bounds__(256) void k_wprep(const float* __restrict__ W1,
                                               const float* __restrict__ W2,
                                               __half* __restrict__ w1frag,
                                               __half* __restrict__ w2frag,
                                               int* __restrict__ bucket_fill) {
    int t = threadIdx.x;
    if (blockIdx.x == 5 && t < NB) bucket_fill[t] = 0;
    int e = blockIdx.x * 256 + t;
    if (e < 1024) {
        int ct = e >> 8, ki = (e >> 6) & 3, l = e & 63;
        int q = l >> 4, n = l & 15;
        v8h o;
        #pragma unroll
        for (int j = 0; j < 8; ++j)
            o[j] = (_Float16)W1[(ki * 32 + q * 8 + j) * 64 + ct * 16 + n];
        ((v8h*)w1frag)[e] = o;
    } else {
        int e2 = e - 1024;
        if (e2 < 384) {
            int ct = e2 >> 7, ki = (e2 >> 6) & 1, l = e2 & 63;
            int q = l >> 4, n = l & 15;
            int col = ct * 16 + n;
            v8h o;
            #pragma unroll
            for (int j = 0; j < 8; ++j)
                o[j] = (col < DOUT) ? (_Float16)W2[(ki * 32 + q * 8 + j) * DOUT + col]
                                    : (_Float16)0.0f;
            ((v8h*)w2frag)[e2] = o;
        }
    }
}

// ---------------- fat kernel: edge scatter (blocks < S_BLKS) || gemm1 (rest) ----------------
__global__ __launch_bounds__(256) void k_fat(const int* __restrict__ src,
                                             const int* __restrict__ dst,
                                             int* __restrict__ bucket_fill,
                                             int* __restrict__ ebuf,
                                             const float* __restrict__ x,
                                             const __half* __restrict__ w1frag,
                                             __half* __restrict__ xw1h) {
    __shared__ int smem[4096];           // 16 KB union
    int t = threadIdx.x;
    if (blockIdx.x < S_BLKS) {
        int* hist  = smem;
        int* gbase = smem + 256;
        int* rcur  = smem + 512;
        for (int i = t; i < NB; i += 256) { hist[i] = 0; rcur[i] = 0; }
        __syncthreads();
        int e0 = blockIdx.x * CH;
        int ep[16], eb[16];
        #pragma unroll
        for (int j = 0; j < 16; ++j) {
            int e = e0 + j * 256 + t;
            bool valid = (e < EE);
            if (valid) {
                int dd_ = dst[e];
                ep[j] = (src[e] << 9) | (dd_ & 511);
                eb[j] = dd_ >> 9;
                atomicAdd(&hist[eb[j]], 1);
            } else {
                ep[j] = 0; eb[j] = -1;
            }
        }
        __syncthreads();
        for (int i = t; i < NB; i += 256)
            gbase[i] = atomicAdd(&bucket_fill[i], hist[i]);
        __syncthreads();
        #pragma unroll
        for (int j = 0; j < 16; ++j) {
            if (eb[j] >= 0) {
                int r = atomicAdd(&rcur[eb[j]], 1);
                ebuf[eb[j] * SEG + gbase[eb[j]] + r] = ep[j];
            }
        }
    } else {
        float4* sb4 = (float4*)smem;     // 1024 float4 = 16 KB
        const float4* wf = (const float4*)w1frag;
        #pragma unroll
        for (int i = 0; i < 4; ++i) sb4[t + i * 256] = wf[t + i * 256];
        __syncthreads();
        const v8h* sbh = (const v8h*)sb4;
        int wv = t >> 6, l = t & 63;
        int q = l >> 4, n = l & 15;
        int row0 = (blockIdx.x - S_BLKS) * 64 + wv * 16;
        int m = row0 + n;
        bool mv = (m < NN);
        const float* xr = x + (size_t)(mv ? m : 0) * DIN + q * 8;
        v8h afrag[4];
        #pragma unroll
        for (int ki = 0; ki < 4; ++ki) {
            float4 u0 = mv ? ((const float4*)(xr + ki * 32))[0] : make_float4(0.f,0.f,0.f,0.f);
            float4 u1 = mv ? ((const float4*)(xr + ki * 32))[1] : make_float4(0.f,0.f,0.f,0.f);
            v8h a;
            a[0] = (_Float16)u0.x; a[1] = (_Float16)u0.y;
            a[2] = (_Float16)u0.z; a[3] = (_Float16)u0.w;
            a[4] = (_Float16)u1.x; a[5] = (_Float16)u1.y;
            a[6] = (_Float16)u1.z; a[7] = (_Float16)u1.w;
            afrag[ki] = a;
        }
        v4f acc[4];
        #pragma unroll
        for (int ct = 0; ct < 4; ++ct) acc[ct] = (v4f){0.f, 0.f, 0.f, 0.f};
        #pragma unroll
        for (int ct = 0; ct < 4; ++ct) {
            #pragma unroll
            for (int ki = 0; ki < 4; ++ki)
                acc[ct] = __builtin_amdgcn_mfma_f32_16x16x32_f16(
                    afrag[ki], sbh[(ct * 4 + ki) * 64 + l], acc[ct], 0, 0, 0);
        }
        _Float16* outh = (_Float16*)xw1h;
        #pragma unroll
        for (int r = 0; r < 4; ++r) {
            int rr = row0 + q * 4 + r;
            if (rr < NN) {
                #pragma unroll
                for (int ct = 0; ct < 4; ++ct)
                    outh[(size_t)rr * HID + ct * 16 + n] = (_Float16)acc[ct][r];
            }
        }
    }
}

// ---------------- per-bucket CSR + dinv (no xw1h pass: gathers scale per-edge) ----------------
__global__ __launch_bounds__(512) void kB_csr(const int* __restrict__ ebuf,
                                              const int* __restrict__ bucket_fill,
                                              int* __restrict__ pofs,
                                              float* __restrict__ dinv,
                                              int* __restrict__ esrc) {
    __shared__ int lcnt[BN], sAa[BN], sBb[BN], lcur[BN];
    int t = threadIdx.x;
    int b = blockIdx.x;
    int eb0 = b * SEG;
    int ecnt = bucket_fill[b];
    lcnt[t] = 0;
    __syncthreads();
    for (int j = t; j < ecnt; j += 512)
        atomicAdd(&lcnt[ebuf[eb0 + j] & 511], 1);
    __syncthreads();
    sAa[t] = lcnt[t];
    __syncthreads();
    int* s = sAa; int* d = sBb;
    for (int off = 1; off < BN; off <<= 1) {
        d[t] = s[t] + ((t >= off) ? s[t - off] : 0);
        __syncthreads();
        int* tmp = s; s = d; d = tmp;
    }
    int base_node = b * BN;
    int excl = s[t] - lcnt[t];
    lcur[t] = excl;
    int node = base_node + t;
    if (node < NN) {
        pofs[node] = ((eb0 + excl) << 10) | lcnt[t];
        dinv[node] = rsqrtf((float)lcnt[t] + 1.0f);   // +1 self-loop
    }
    __syncthreads();
    for (int j = t; j < ecnt; j += 512) {
        int p = ebuf[eb0 + j];
        int r = atomicAdd(&lcur[p & 511], 1);
        // pack: bits 0..16 = src node, bits 17..25 = bucket-local dst
        esrc[eb0 + r] = (p >> 9) | ((p & 511) << 17);
    }
}

// ---------------- fused: layer-1 aggregation (per-edge dinv scale) + layer-2 GEMM ----------------
// Phase A: 32 groups x 8 lanes; group g owns dsts d0+2g, d0+2g+1 (adjacent CSR
// ranges -> one contiguous span). Table is UNSCALED; per-edge dinv[src] loaded
// with the gathers and folded into the existing fma pair (zero extra VALU).
// Phase B: 4 waves x 16 rows; A-frags from LDS halves (+bias+relu), 6 MFMAs;
// epilogue writes PACKED 40-half rows of hw2p, pre-scaled by dinv[row].
__global__ __launch_bounds__(256) void k_fuse(const __half* __restrict__ xw1h,
                                              const float* __restrict__ dinv,
                                              const int* __restrict__ pofs,
                                              const int* __restrict__ esrc,
                                              const float* __restrict__ b1,
                                              const __half* __restrict__ w2frag,
                                              __half* __restrict__ hw2p) {
    __shared__ __half sh[64 * 72];       // 9 KB agg rows (stride 144 B, 16B-aligned)
    __shared__ float4 sb4[384];          // 6 KB: W2 B-frags
    __shared__ float sb1[64];
    int t = threadIdx.x;
    const float4* wf = (const float4*)w2frag;
    if (t < 192) { sb4[t] = wf[t]; sb4[t + 192] = wf[t + 192]; }
    if (t >= 192) sb1[t - 192] = b1[t - 192];

    int d0 = blockIdx.x * 64;
    int g = t >> 3, q = t & 7;
    int dA = d0 + 2 * g;                 // NN even: dA < NN implies dA+1 < NN
    const float4* tab4 = (const float4*)xw1h;
    float4 tl = make_float4(0.f,0.f,0.f,0.f), th = make_float4(0.f,0.f,0.f,0.f);
    float4 bl = make_float4(0.f,0.f,0.f,0.f), bh = make_float4(0.f,0.f,0.f,0.f);
    if (dA < NN) {
        int pA_ = pofs[dA], pB_ = pofs[dA + 1];
        int j  = pA_ >> 10;
        int je = (pB_ >> 10) + (pB_ & 1023);       // contiguous combined span
        float diA = dinv[dA], diB = dinv[dA + 1];
        float4 sA = tab4[(size_t)dA * 8 + q];      // self-loops (unscaled rows)
        float4 sB = tab4[(size_t)(dA + 1) * 8 + q];
        fma8(sA, diA, tl, th);
        fma8(sB, diB, tl, th);
        fma8(sB, diB, bl, bh);
        agg_span1(tab4, dinv, esrc, j, je, q, tl, th, bl, bh);
        float4 al = make_float4(tl.x - bl.x, tl.y - bl.y, tl.z - bl.z, tl.w - bl.w);
        float4 ah = make_float4(th.x - bh.x, th.y - bh.y, th.z - bh.z, th.w - bh.w);
        sthalf8(sh + (2 * g) * 72 + q * 8, al, ah, diA);
        sthalf8(sh + (2 * g + 1) * 72 + q * 8, bl, bh, diB);
    } else {
        float4 z = make_float4(0.f,0.f,0.f,0.f);
        sthalf8(sh + (2 * g) * 72 + q * 8, z, z, 0.f);
        sthalf8(sh + (2 * g + 1) * 72 + q * 8, z, z, 0.f);
    }
    __syncthreads();

    // phase B: 4 waves x 16 rows, A from LDS (+bias+relu), 6 MFMAs
    const v8h* sbh = (const v8h*)sb4;
    int wv = t >> 6, l = t & 63;
    int qq = l >> 4, n = l & 15;
    int srow = wv * 16 + n;
    v8h afrag[2];
    #pragma unroll
    for (int ki = 0; ki < 2; ++ki) {
        v8h a = *(const v8h*)(sh + srow * 72 + ki * 32 + qq * 8);
        #pragma unroll
        for (int jj = 0; jj < 8; ++jj) {
            float av = (float)a[jj] + sb1[ki * 32 + qq * 8 + jj];
            a[jj] = (_Float16)fmaxf(av, 0.f);
        }
        afrag[ki] = a;
    }
    v4f acc[3];
    #pragma unroll
    for (int ct = 0; ct < 3; ++ct) acc[ct] = (v4f){0.f, 0.f, 0.f, 0.f};
    #pragma unroll
    for (int ct = 0; ct < 3; ++ct) {
        #pragma unroll
        for (int ki = 0; ki < 2; ++ki)
            acc[ct] = __builtin_amdgcn_mfma_f32_16x16x32_f16(
                afrag[ki], sbh[(ct * 2 + ki) * 64 + l], acc[ct], 0, 0, 0);
    }
    // packed 40-half rows, pre-scaled by dinv[row]
    _Float16* outh = (_Float16*)hw2p;
    #pragma unroll
    for (int r = 0; r < 4; ++r) {
        int rr = d0 + wv * 16 + qq * 4 + r;
        if (rr < NN) {
            float di = dinv[rr];
            outh[(size_t)rr * 40 + n]      = (_Float16)(acc[0][r] * di);
            outh[(size_t)rr * 40 + 16 + n] = (_Float16)(acc[1][r] * di);
            if (n < 8)
                outh[(size_t)rr * 40 + 32 + n] = (_Float16)(acc[2][r] * di);
        }
    }
}

// ---------------- layer 2 aggregation: packed 80B rows, dual-dst, pipelined ----------------
__global__ __launch_bounds__(256) void k_agg2(const __half* __restrict__ hw2p,
                                              const float* __restrict__ dinv,
                                              const int* __restrict__ pofs,
                                              const int* __restrict__ esrc,
                                              const float* __restrict__ b2,
                                              float* __restrict__ out) {
    int t = threadIdx.x;
    int g = t >> 3, q = t & 7;
    int qc = (q < 5) ? q : (q - 3);      // lanes 5-7 duplicate granules 2-4 (coalescer merges)
    int d0 = blockIdx.x * 64;
    int dA = d0 + 2 * g;
    if (dA >= NN) return;                // no __syncthreads below: safe early-out
    const float4* tab4 = (const float4*)hw2p;
    float4 tl = make_float4(0.f,0.f,0.f,0.f), th = make_float4(0.f,0.f,0.f,0.f);
    float4 bl = make_float4(0.f,0.f,0.f,0.f), bh = make_float4(0.f,0.f,0.f,0.f);
    int pA_ = pofs[dA], pB_ = pofs[dA + 1];
    int j  = pA_ >> 10;
    int je = (pB_ >> 10) + (pB_ & 1023);
    float4 sA = tab4[(size_t)dA * 5 + qc];
    float4 sB = tab4[(size_t)(dA + 1) * 5 + qc];
    acc8(sA, tl, th);
    acc8(sB, tl, th);
    acc8(sB, bl, bh);
    agg_span2(tab4, esrc, j, je, qc, tl, th, bl, bh);
    if (q < 5) {                         // channels q*8 .. q*8+7 (40 total)
        float diA = dinv[dA], diB = dinv[dA + 1];
        const float4* b24 = (const float4*)(b2 + q * 8);
        float4 c0 = b24[0], c1 = b24[1];
        float* opA = out + (size_t)dA * DOUT + q * 8;
        ((float4*)opA)[0] = make_float4((tl.x - bl.x) * diA + c0.x, (tl.y - bl.y) * diA + c0.y,
                                        (tl.z - bl.z) * diA + c0.z, (tl.w - bl.w) * diA + c0.w);
        ((float4*)opA)[1] = make_float4((th.x - bh.x) * diA + c1.x, (th.y - bh.y) * diA + c1.y,
                                        (th.z - bh.z) * diA + c1.z, (th.w - bh.w) * diA + c1.w);
        float* opB = out + (size_t)(dA + 1) * DOUT + q * 8;
        ((float4*)opB)[0] = make_float4(bl.x * diB + c0.x, bl.y * diB + c0.y,
                                        bl.z * diB + c0.z, bl.w * diB + c0.w);
        ((float4*)opB)[1] = make_float4(bh.x * diB + c1.x, bh.y * diB + c1.y,
                                        bh.z * diB + c1.z, bh.w * diB + c1.w);
    }
}

extern "C" void kernel_launch(void* const* d_in, const int* in_sizes, int n_in,
                              void* d_out, int out_size, void* d_ws, size_t ws_size,
                              hipStream_t stream) {
    const float* x  = (const float*)d_in[0];
    const float* W1 = (const float*)d_in[1];
    const float* b1 = (const float*)d_in[2];
    const float* W2 = (const float*)d_in[3];
    const float* b2 = (const float*)d_in[4];
    const int*   ei = (const int*)d_in[5];
    const int* src = ei;        // edge_index[0]
    const int* dst = ei + EE;   // edge_index[1]
    float* out = (float*)d_out;

    float* ws = (float*)d_ws;
    int*    bucket_fill = (int*)ws;                     // [0,256)
    int*    pofs        = (int*)ws + 256;               // NN
    float*  dinv        = ws + 100352;                  // NN
    int*    ebuf        = (int*)ws + 200704;            // NB*SEG = 1605632
    int*    esrc        = (int*)ws + 1806336;           // NB*SEG
    __half* xw1h        = (__half*)(ws + 3411968);      // NN*64 halves (UNSCALED)
    __half* hw2p        = (__half*)(ws + 6611968);      // NN*40 halves (packed, pre-scaled)
    __half* w1frag      = (__half*)(ws + 9811968);      // 8192 halves
    __half* w2frag      = (__half*)(ws + 9816064);      // 3072 halves
    // total: 9,817,600 floats = 39.3 MB

    k_wprep <<<6, 256, 0, stream>>>(W1, W2, w1frag, w2frag, bucket_fill);
    k_fat   <<<S_BLKS + G_BLKS, 256, 0, stream>>>(src, dst, bucket_fill, ebuf, x, w1frag, xw1h);
    kB_csr  <<<NB, 512, 0, stream>>>(ebuf, bucket_fill, pofs, dinv, esrc);
    k_fuse  <<<(NN + 63) / 64, 256, 0, stream>>>(xw1h, dinv, pofs, esrc, b1, w2frag, hw2p);
    k_agg2  <<<(NN + 63) / 64, 256, 0, stream>>>(hw2p, dinv, pofs, esrc, b2, out);
}

// Round 6
// 204.617 us; speedup vs baseline: 1.0172x; 1.0172x over previous
//
#include <hip/hip_runtime.h>
#include <hip/hip_fp16.h>

#define NN   100000
#define EE   1250000
#define DIN  128
#define HID  64
#define DOUT 40

#define BN   512                  // nodes per bucket
#define NB   196                  // ceil(NN/BN)
#define CH   4096                 // edges per scatter block (16/thread)
#define SEG  8192                 // padded bucket capacity (mean 6377, 22 sigma)
#define S_BLKS 306                // ceil(EE/CH)
#define G_BLKS 1563               // ceil(NN/64)

typedef _Float16 v8h __attribute__((ext_vector_type(8)));
typedef float    v4f __attribute__((ext_vector_type(4)));

// unpack a float4-of-8-halves and accumulate into 2 float4s
__device__ __forceinline__ void acc8(const float4& v, float4& lo, float4& hi) {
    const __half2* hp = (const __half2*)&v;
    float2 f0 = __half22float2(hp[0]), f1 = __half22float2(hp[1]);
    float2 f2 = __half22float2(hp[2]), f3 = __half22float2(hp[3]);
    lo.x += f0.x; lo.y += f0.y; lo.z += f1.x; lo.w += f1.y;
    hi.x += f2.x; hi.y += f2.y; hi.z += f3.x; hi.w += f3.y;
}

// predicated/scaled accumulate: acc += v * s
__device__ __forceinline__ void fma8(const float4& v, float s, float4& lo, float4& hi) {
    const __half2* hp = (const __half2*)&v;
    float2 f0 = __half22float2(hp[0]), f1 = __half22float2(hp[1]);
    float2 f2 = __half22float2(hp[2]), f3 = __half22float2(hp[3]);
    lo.x += f0.x * s; lo.y += f0.y * s; lo.z += f1.x * s; lo.w += f1.y * s;
    hi.x += f2.x * s; hi.y += f2.y * s; hi.z += f3.x * s; hi.w += f3.y * s;
}

// scale by d, convert to 8 halves, store 16B
__device__ __forceinline__ void sthalf8(__half* p, const float4& lo, const float4& hi, float d) {
    float4 st;
    __half2* hp = (__half2*)&st;
    hp[0] = __floats2half2_rn(lo.x * d, lo.y * d);
    hp[1] = __floats2half2_rn(lo.z * d, lo.w * d);
    hp[2] = __floats2half2_rn(hi.x * d, hi.y * d);
    hp[3] = __floats2half2_rn(hi.z * d, hi.w * d);
    *(float4*)p = st;
}

// ---- software-pipelined gather helpers ----
__device__ __forceinline__ void load8(const int* __restrict__ esrc, int base, int* e) {
#pragma unroll
    for (int u = 0; u < 8; ++u) e[u] = esrc[base + u];
}

// layer-1 (pre-scaled 128B rows): gathers + sel bits (frees id regs)
__device__ __forceinline__ void gath8(const float4* __restrict__ tab4, const int* e, int q,
                                      float4* v, int& s) {
#pragma unroll
    for (int u = 0; u < 8; ++u) v[u] = tab4[(size_t)(e[u] & 0x1FFFF) * 8 + q];
    s = 0;
#pragma unroll
    for (int u = 0; u < 8; ++u) s |= ((e[u] >> 17) & 1) << u;
}

// layer-2 (packed 80B rows, pre-scaled): gathers + sel bits
__device__ __forceinline__ void gath8p(const float4* __restrict__ tab4,
                                       const int* e, int qc, float4* v, int& s) {
#pragma unroll
    for (int u = 0; u < 8; ++u) v[u] = tab4[(size_t)(e[u] & 0x1FFFF) * 5 + qc];
    s = 0;
#pragma unroll
    for (int u = 0; u < 8; ++u) s |= ((e[u] >> 17) & 1) << u;
}

__device__ __forceinline__ void unp8(const float4* v, int s,
                                     float4& tl, float4& th, float4& bl, float4& bh) {
#pragma unroll
    for (int u = 0; u < 8; ++u) {
        float su = (float)((s >> u) & 1);
        acc8(v[u], tl, th);
        fma8(v[u], su, bl, bh);
    }
}

// 2-deep ping-pong pipelined aggregation, layer-1 (pre-scaled 128B-row table).
// ids(m+1) issued BEFORE gathers(m): counted vmcnt for ids never drains gathers.
__device__ __forceinline__ void agg_span(const float4* __restrict__ tab4,
                                         const int* __restrict__ esrc,
                                         int j, int je, int q,
                                         float4& tl, float4& th, float4& bl, float4& bh) {
    int eA[8], eB[8];
    float4 vA[8], vB[8];
    int sA, sB;
    int n8 = (je - j) >> 3;
    if (n8 > 0) {
        int lastb = j + (n8 - 1) * 8;
        load8(esrc, j, eA);
        gath8(tab4, eA, q, vA, sA);
        if (n8 == 1) {
            unp8(vA, sA, tl, th, bl, bh);
        } else {
            load8(esrc, j + 8, eB);
            int m = 1;
            while (true) {
                load8(esrc, min(j + (m + 1) * 8, lastb), eA);
                gath8(tab4, eB, q, vB, sB);
                unp8(vA, sA, tl, th, bl, bh);
                ++m;
                if (m >= n8) { unp8(vB, sB, tl, th, bl, bh); break; }
                load8(esrc, min(j + (m + 1) * 8, lastb), eB);
                gath8(tab4, eA, q, vA, sA);
                unp8(vB, sB, tl, th, bl, bh);
                ++m;
                if (m >= n8) { unp8(vA, sA, tl, th, bl, bh); break; }
            }
        }
        j += n8 << 3;
    }
    for (; j < je; ++j) {
        int e = esrc[j];
        float4 v = tab4[(size_t)(e & 0x1FFFF) * 8 + q];
        float su = (float)((e >> 17) & 1);
        acc8(v, tl, th);
        fma8(v, su, bl, bh);
    }
}

// 2-deep ping-pong pipelined aggregation, layer-2 (packed pre-scaled 80B rows)
__device__ __forceinline__ void agg_span2(const float4* __restrict__ tab4,
                                          const int* __restrict__ esrc,
                                          int j, int je, int qc,
                                          float4& tl, float4& th, float4& bl, float4& bh) {
    int eA[8], eB[8];
    float4 vA[8], vB[8];
    int sA, sB;
    int n8 = (je - j) >> 3;
    if (n8 > 0) {
        int lastb = j + (n8 - 1) * 8;
        load8(esrc, j, eA);
        gath8p(tab4, eA, qc, vA, sA);
        if (n8 == 1) {
            unp8(vA, sA, tl, th, bl, bh);
        } else {
            load8(esrc, j + 8, eB);
            int m = 1;
            while (true) {
                load8(esrc, min(j + (m + 1) * 8, lastb), eA);
                gath8p(tab4, eB, qc, vB, sB);
                unp8(vA, sA, tl, th, bl, bh);
                ++m;
                if (m >= n8) { unp8(vB, sB, tl, th, bl, bh); break; }
                load8(esrc, min(j + (m + 1) * 8, lastb), eB);
                gath8p(tab4, eA, qc, vA, sA);
                unp8(vB, sB, tl, th, bl, bh);
                ++m;
                if (m >= n8) { unp8(vA, sA, tl, th, bl, bh); break; }
            }
        }
        j += n8 << 3;
    }
    for (; j < je; ++j) {
        int e = esrc[j];
        float4 v = tab4[(size_t)(e & 0x1FFFF) * 5 + qc];
        float su = (float)((e >> 17) & 1);
        acc8(v, tl, th);
        fma8(v, su, bl, bh);
    }
}

// ---------------- W1 & W2 -> B-fragment pre-pack + bucket_fill zero ----------------
__global__ __launch_bounds__(256) void k_wprep(const float* __restrict__ W1,
                                               const float* __restrict__ W2,
                                               __half* __restrict__ w1frag,
                                               __half* __restrict__ w2frag,
                                               int* __restrict__ bucket_fill) {
    int t = threadIdx.x;
    if (blockIdx.x == 5 && t < NB) bucket_fill[t] = 0;
    int e = blockIdx.x * 256 + t;
    if (e < 1024) {
        int ct = e >> 8, ki = (e >> 6) & 3, l = e & 63;
        int q = l >> 4, n = l & 15;
        v8h o;
        #pragma unroll
        for (int j = 0; j < 8; ++j)
            o[j] = (_Float16)W1[(ki * 32 + q * 8 + j) * 64 + ct * 16 + n];
        ((v8h*)w1frag)[e] = o;
    } else {
        int e2 = e - 1024;
        if (e2 < 384) {
            int ct = e2 >> 7, ki = (e2 >> 6) & 1, l = e2 & 63;
            int q = l >> 4, n = l & 15;
            int col = ct * 16 + n;
            v8h o;
            #pragma unroll
            for (int j = 0; j < 8; ++j)
                o[j] = (col < DOUT) ? (_Float16)W2[(ki * 32 + q * 8 + j) * DOUT + col]
                                    : (_Float16)0.0f;
            ((v8h*)w2frag)[e2] = o;
        }
    }
}

// ---------------- fat kernel: edge scatter (blocks < S_BLKS) || gemm1 (rest) ----------------
__global__ __launch_bounds__(256) void k_fat(const int* __restrict__ src,
                                             const int* __restrict__ dst,
                                             int* __restrict__ bucket_fill,
                                             int* __restrict__ ebuf,
                                             const float* __restrict__ x,
                                             const __half* __restrict__ w1frag,
                                             __half* __restrict__ xw1h) {
    __shared__ int smem[4096];           // 16 KB union
    int t = threadIdx.x;
    if (blockIdx.x < S_BLKS) {
        int* hist  = smem;
        int* gbase = smem + 256;
        int* rcur  = smem + 512;
        for (int i = t; i < NB; i += 256) { hist[i] = 0; rcur[i] = 0; }
        __syncthreads();
        int e0 = blockIdx.x * CH;
        int ep[16], eb[16];
        #pragma unroll
        for (int j = 0; j < 16; ++j) {
            int e = e0 + j * 256 + t;
            bool valid = (e < EE);
            if (valid) {
                int dd_ = dst[e];
                ep[j] = (src[e] << 9) | (dd_ & 511);
                eb[j] = dd_ >> 9;
                atomicAdd(&hist[eb[j]], 1);
            } else {
                ep[j] = 0; eb[j] = -1;
            }
        }
        __syncthreads();
        for (int i = t; i < NB; i += 256)
            gbase[i] = atomicAdd(&bucket_fill[i], hist[i]);
        __syncthreads();
        #pragma unroll
        for (int j = 0; j < 16; ++j) {
            if (eb[j] >= 0) {
                int r = atomicAdd(&rcur[eb[j]], 1);
                ebuf[eb[j] * SEG + gbase[eb[j]] + r] = ep[j];
            }
        }
    } else {
        float4* sb4 = (float4*)smem;     // 1024 float4 = 16 KB
        const float4* wf = (const float4*)w1frag;
        #pragma unroll
        for (int i = 0; i < 4; ++i) sb4[t + i * 256] = wf[t + i * 256];
        __syncthreads();
        const v8h* sbh = (const v8h*)sb4;
        int wv = t >> 6, l = t & 63;
        int q = l >> 4, n = l & 15;
        int row0 = (blockIdx.x - S_BLKS) * 64 + wv * 16;
        int m = row0 + n;
        bool mv = (m < NN);
        const float* xr = x + (size_t)(mv ? m : 0) * DIN + q * 8;
        v8h afrag[4];
        #pragma unroll
        for (int ki = 0; ki < 4; ++ki) {
            float4 u0 = mv ? ((const float4*)(xr + ki * 32))[0] : make_float4(0.f,0.f,0.f,0.f);
            float4 u1 = mv ? ((const float4*)(xr + ki * 32))[1] : make_float4(0.f,0.f,0.f,0.f);
            v8h a;
            a[0] = (_Float16)u0.x; a[1] = (_Float16)u0.y;
            a[2] = (_Float16)u0.z; a[3] = (_Float16)u0.w;
            a[4] = (_Float16)u1.x; a[5] = (_Float16)u1.y;
            a[6] = (_Float16)u1.z; a[7] = (_Float16)u1.w;
            afrag[ki] = a;
        }
        v4f acc[4];
        #pragma unroll
        for (int ct = 0; ct < 4; ++ct) acc[ct] = (v4f){0.f, 0.f, 0.f, 0.f};
        #pragma unroll
        for (int ct = 0; ct < 4; ++ct) {
            #pragma unroll
            for (int ki = 0; ki < 4; ++ki)
                acc[ct] = __builtin_amdgcn_mfma_f32_16x16x32_f16(
                    afrag[ki], sbh[(ct * 4 + ki) * 64 + l], acc[ct], 0, 0, 0);
        }
        _Float16* outh = (_Float16*)xw1h;
        #pragma unroll
        for (int r = 0; r < 4; ++r) {
            int rr = row0 + q * 4 + r;
            if (rr < NN) {
                #pragma unroll
                for (int ct = 0; ct < 4; ++ct)
                    outh[(size_t)rr * HID + ct * 16 + n] = (_Float16)acc[ct][r];
            }
        }
    }
}

// ---------------- per-bucket CSR + dinv + xw1h scaling (512 threads) ----------------
__global__ __launch_bounds__(512) void kB_csr(const int* __restrict__ ebuf,
                                              const int* __restrict__ bucket_fill,
                                              int* __restrict__ pofs,
                                              float* __restrict__ dinv,
                                              int* __restrict__ esrc,
                                              __half* __restrict__ xw1h) {
    __shared__ int lcnt[BN], sAa[BN], sBb[BN], lcur[BN];
    int t = threadIdx.x;
    int b = blockIdx.x;
    int eb0 = b * SEG;
    int ecnt = bucket_fill[b];
    lcnt[t] = 0;
    __syncthreads();
    for (int j = t; j < ecnt; j += 512)
        atomicAdd(&lcnt[ebuf[eb0 + j] & 511], 1);
    __syncthreads();
    sAa[t] = lcnt[t];
    __syncthreads();
    int* s = sAa; int* d = sBb;
    for (int off = 1; off < BN; off <<= 1) {
        d[t] = s[t] + ((t >= off) ? s[t - off] : 0);
        __syncthreads();
        int* tmp = s; s = d; d = tmp;
    }
    int base_node = b * BN;
    int excl = s[t] - lcnt[t];
    lcur[t] = excl;
    int node = base_node + t;
    if (node < NN) {
        pofs[node] = ((eb0 + excl) << 10) | lcnt[t];
        dinv[node] = rsqrtf((float)lcnt[t] + 1.0f);   // +1 self-loop
    }
    __syncthreads();
    for (int j = t; j < ecnt; j += 512) {
        int p = ebuf[eb0 + j];
        int r = atomicAdd(&lcur[p & 511], 1);
        // pack: bits 0..16 = src node, bits 17..25 = bucket-local dst
        esrc[eb0 + r] = (p >> 9) | ((p & 511) << 17);
    }
    // scale this bucket's xw1h rows by dinv (k_fat wrote them unscaled):
    // gathers then need NO per-edge scale loads (proven faster, R4 vs R5)
    float4* xr4 = (float4*)xw1h;
    for (int i = t; i < BN * 8; i += 512) {
        int li = i >> 3;
        int node2 = base_node + li;
        if (node2 < NN) {
            float di = rsqrtf((float)lcnt[li] + 1.0f);
            float4 v = xr4[(size_t)node2 * 8 + (i & 7)];
            __half2* h = (__half2*)&v;
            #pragma unroll
            for (int u = 0; u < 4; ++u) {
                float2 f = __half22float2(h[u]);
                h[u] = __floats2half2_rn(f.x * di, f.y * di);
            }
            xr4[(size_t)node2 * 8 + (i & 7)] = v;
        }
    }
}

// ---------------- fused: layer-1 aggregation (pre-scaled table, pipelined) + layer-2 GEMM ----------------
// Phase A: 32 groups x 8 lanes; group g owns dsts d0+2g, d0+2g+1 (adjacent CSR
// ranges -> one contiguous span). Table pre-scaled by dinv[src] -> gathers only.
// Phase B: 4 waves x 16 rows; A-frags from LDS halves (+bias+relu), 6 MFMAs;
// epilogue writes PACKED 40-half rows of hw2p, pre-scaled by dinv[row].
__global__ __launch_bounds__(256) void k_fuse(const __half* __restrict__ xw1h,
                                              const float* __restrict__ dinv,
                                              const int* __restrict__ pofs,
                                              const int* __restrict__ esrc,
                                              const float* __restrict__ b1,
                                              const __half* __restrict__ w2frag,
                                              __half* __restrict__ hw2p) {
    __shared__ __half sh[64 * 72];       // 9 KB agg rows (stride 144 B, 16B-aligned)
    __shared__ float4 sb4[384];          // 6 KB: W2 B-frags
    __shared__ float sb1[64];
    int t = threadIdx.x;
    const float4* wf = (const float4*)w2frag;
    if (t < 192) { sb4[t] = wf[t]; sb4[t + 192] = wf[t + 192]; }
    if (t >= 192) sb1[t - 192] = b1[t - 192];

    int d0 = blockIdx.x * 64;
    int g = t >> 3, q = t & 7;
    int dA = d0 + 2 * g;                 // NN even: dA < NN implies dA+1 < NN
    const float4* tab4 = (const float4*)xw1h;
    float4 tl = make_float4(0.f,0.f,0.f,0.f), th = make_float4(0.f,0.f,0.f,0.f);
    float4 bl = make_float4(0.f,0.f,0.f,0.f), bh = make_float4(0.f,0.f,0.f,0.f);
    if (dA < NN) {
        int pA_ = pofs[dA], pB_ = pofs[dA + 1];
        int j  = pA_ >> 10;
        int je = (pB_ >> 10) + (pB_ & 1023);       // contiguous combined span
        float4 sA = tab4[(size_t)dA * 8 + q];      // self-loops (rows pre-scaled by dinv[src])
        float4 sB = tab4[(size_t)(dA + 1) * 8 + q];
        acc8(sA, tl, th);
        acc8(sB, tl, th);
        acc8(sB, bl, bh);
        agg_span(tab4, esrc, j, je, q, tl, th, bl, bh);
        float diA = dinv[dA], diB = dinv[dA + 1];
        float4 al = make_float4(tl.x - bl.x, tl.y - bl.y, tl.z - bl.z, tl.w - bl.w);
        float4 ah = make_float4(th.x - bh.x, th.y - bh.y, th.z - bh.z, th.w - bh.w);
        sthalf8(sh + (2 * g) * 72 + q * 8, al, ah, diA);
        sthalf8(sh + (2 * g + 1) * 72 + q * 8, bl, bh, diB);
    } else {
        float4 z = make_float4(0.f,0.f,0.f,0.f);
        sthalf8(sh + (2 * g) * 72 + q * 8, z, z, 0.f);
        sthalf8(sh + (2 * g + 1) * 72 + q * 8, z, z, 0.f);
    }
    __syncthreads();

    // phase B: 4 waves x 16 rows, A from LDS (+bias+relu), 6 MFMAs
    const v8h* sbh = (const v8h*)sb4;
    int wv = t >> 6, l = t & 63;
    int qq = l >> 4, n = l & 15;
    int srow = wv * 16 + n;
    v8h afrag[2];
    #pragma unroll
    for (int ki = 0; ki < 2; ++ki) {
        v8h a = *(const v8h*)(sh + srow * 72 + ki * 32 + qq * 8);
        #pragma unroll
        for (int jj = 0; jj < 8; ++jj) {
            float av = (float)a[jj] + sb1[ki * 32 + qq * 8 + jj];
            a[jj] = (_Float16)fmaxf(av, 0.f);
        }
        afrag[ki] = a;
    }
    v4f acc[3];
    #pragma unroll
    for (int ct = 0; ct < 3; ++ct) acc[ct] = (v4f){0.f, 0.f, 0.f, 0.f};
    #pragma unroll
    for (int ct = 0; ct < 3; ++ct) {
        #pragma unroll
        for (int ki = 0; ki < 2; ++ki)
            acc[ct] = __builtin_amdgcn_mfma_f32_16x16x32_f16(
                afrag[ki], sbh[(ct * 2 + ki) * 64 + l], acc[ct], 0, 0, 0);
    }
    // packed 40-half rows, pre-scaled by dinv[row]
    _Float16* outh = (_Float16*)hw2p;
    #pragma unroll
    for (int r = 0; r < 4; ++r) {
        int rr = d0 + wv * 16 + qq * 4 + r;
        if (rr < NN) {
            float di = dinv[rr];
            outh[(size_t)rr * 40 + n]      = (_Float16)(acc[0][r] * di);
            outh[(size_t)rr * 40 + 16 + n] = (_Float16)(acc[1][r] * di);
            if (n < 8)
                outh[(size_t)rr * 40 + 32 + n] = (_Float16)(acc[2][r] * di);
        }
    }
}

// ---------------- layer 2 aggregation: packed 80B rows, dual-dst, pipelined ----------------
__global__ __launch_bounds__(256) void k_agg2(const __half* __restrict__ hw2p,
                                              const float* __restrict__ dinv,
                                              const int* __restrict__ pofs,
                                              const int* __restrict__ esrc,
                                              const float* __restrict__ b2,
                                              float* __restrict__ out) {
    int t = threadIdx.x;
    int g = t >> 3, q = t & 7;
    int qc = (q < 5) ? q : (q - 3);      // lanes 5-7 duplicate granules 2-4 (coalescer merges)
    int d0 = blockIdx.x * 64;
    int dA = d0 + 2 * g;
    if (dA >= NN) return;                // no __syncthreads below: safe early-out
    const float4* tab4 = (const float4*)hw2p;
    float4 tl = make_float4(0.f,0.f,0.f,0.f), th = make_float4(0.f,0.f,0.f,0.f);
    float4 bl = make_float4(0.f,0.f,0.f,0.f), bh = make_float4(0.f,0.f,0.f,0.f);
    int pA_ = pofs[dA], pB_ = pofs[dA + 1];
    int j  = pA_ >> 10;
    int je = (pB_ >> 10) + (pB_ & 1023);
    float4 sA = tab4[(size_t)dA * 5 + qc];
    float4 sB = tab4[(size_t)(dA + 1) * 5 + qc];
    acc8(sA, tl, th);
    acc8(sB, tl, th);
    acc8(sB, bl, bh);
    agg_span2(tab4, esrc, j, je, qc, tl, th, bl, bh);
    if (q < 5) {                         // channels q*8 .. q*8+7 (40 total)
        float diA = dinv[dA], diB = dinv[dA + 1];
        const float4* b24 = (const float4*)(b2 + q * 8);
        float4 c0 = b24[0], c1 = b24[1];
        float* opA = out + (size_t)dA * DOUT + q * 8;
        ((float4*)opA)[0] = make_float4((tl.x - bl.x) * diA + c0.x, (tl.y - bl.y) * diA + c0.y,
                                        (tl.z - bl.z) * diA + c0.z, (tl.w - bl.w) * diA + c0.w);
        ((float4*)opA)[1] = make_float4((th.x - bh.x) * diA + c1.x, (th.y - bh.y) * diA + c1.y,
                                        (th.z - bh.z) * diA + c1.z, (th.w - bh.w) * diA + c1.w);
        float* opB = out + (size_t)(dA + 1) * DOUT + q * 8;
        ((float4*)opB)[0] = make_float4(bl.x * diB + c0.x, bl.y * diB + c0.y,
                                        bl.z * diB + c0.z, bl.w * diB + c0.w);
        ((float4*)opB)[1] = make_float4(bh.x * diB + c1.x, bh.y * diB + c1.y,
                                        bh.z * diB + c1.z, bh.w * diB + c1.w);
    }
}

extern "C" void kernel_launch(void* const* d_in, const int* in_sizes, int n_in,
                              void* d_out, int out_size, void* d_ws, size_t ws_size,
                              hipStream_t stream) {
    const float* x  = (const float*)d_in[0];
    const float* W1 = (const float*)d_in[1];
    const float* b1 = (const float*)d_in[2];
    const float* W2 = (const float*)d_in[3];
    const float* b2 = (const float*)d_in[4];
    const int*   ei = (const int*)d_in[5];
    const int* src = ei;        // edge_index[0]
    const int* dst = ei + EE;   // edge_index[1]
    float* out = (float*)d_out;

    float* ws = (float*)d_ws;
    int*    bucket_fill = (int*)ws;                     // [0,256)
    int*    pofs        = (int*)ws + 256;               // NN
    float*  dinv        = ws + 100352;                  // NN
    int*    ebuf        = (int*)ws + 200704;            // NB*SEG = 1605632
    int*    esrc        = (int*)ws + 1806336;           // NB*SEG
    __half* xw1h        = (__half*)(ws + 3411968);      // NN*64 halves (pre-scaled by kB_csr)
    __half* hw2p        = (__half*)(ws + 6611968);      // NN*40 halves (packed, pre-scaled)
    __half* w1frag      = (__half*)(ws + 9811968);      // 8192 halves
    __half* w2frag      = (__half*)(ws + 9816064);      // 3072 halves
    // total: 9,817,600 floats = 39.3 MB

    k_wprep <<<6, 256, 0, stream>>>(W1, W2, w1frag, w2frag, bucket_fill);
    k_fat   <<<S_BLKS + G_BLKS, 256, 0, stream>>>(src, dst, bucket_fill, ebuf, x, w1frag, xw1h);
    kB_csr  <<<NB, 512, 0, stream>>>(ebuf, bucket_fill, pofs, dinv, esrc, xw1h);
    k_fuse  <<<(NN + 63) / 64, 256, 0, stream>>>(xw1h, dinv, pofs, esrc, b1, w2frag, hw2p);
    k_agg2  <<<(NN + 63) / 64, 256, 0, stream>>>(hw2p, dinv, pofs, esrc, b2, out);
}

// Round 7
// 182.070 us; speedup vs baseline: 1.1432x; 1.1238x over previous
//
#include <hip/hip_runtime.h>
#include <hip/hip_fp16.h>

#define NN   100000
#define EE   1250000
#define DIN  128
#define HID  64
#define DOUT 40

#define BN   512                  // nodes per bucket
#define NB   196                  // ceil(NN/BN)
#define CH   4096                 // edges per scatter block (16/thread)
#define SEG  8192                 // ebuf stride (raw edges; mean 6377, 22 sigma)
#define SEG2 10240                // esrc stride (8-padded lists; mean ~8280, >10 sigma margin)
#define S_BLKS 306                // ceil(EE/CH)
#define G_BLKS 1563               // ceil(NN/64)

typedef _Float16 v8h __attribute__((ext_vector_type(8)));
typedef float    v4f __attribute__((ext_vector_type(4)));

// unpack a float4-of-8-halves and accumulate into 2 float4s
__device__ __forceinline__ void acc8(const float4& v, float4& lo, float4& hi) {
    const __half2* hp = (const __half2*)&v;
    float2 f0 = __half22float2(hp[0]), f1 = __half22float2(hp[1]);
    float2 f2 = __half22float2(hp[2]), f3 = __half22float2(hp[3]);
    lo.x += f0.x; lo.y += f0.y; lo.z += f1.x; lo.w += f1.y;
    hi.x += f2.x; hi.y += f2.y; hi.z += f3.x; hi.w += f3.y;
}

// scale by d, convert to 8 halves, store 16B
__device__ __forceinline__ void sthalf8(__half* p, const float4& lo, const float4& hi, float d) {
    float4 st;
    __half2* hp = (__half2*)&st;
    hp[0] = __floats2half2_rn(lo.x * d, lo.y * d);
    hp[1] = __floats2half2_rn(lo.z * d, lo.w * d);
    hp[2] = __floats2half2_rn(hi.x * d, hi.y * d);
    hp[3] = __floats2half2_rn(hi.z * d, hi.w * d);
    *(float4*)p = st;
}

// ---------------- W1 & W2 -> B-fragment pre-pack + bucket_fill zero + zero rows ----------------
__global__ __launch_bounds__(256) void k_wprep(const float* __restrict__ W1,
                                               const float* __restrict__ W2,
                                               __half* __restrict__ w1frag,
                                               __half* __restrict__ w2frag,
                                               int* __restrict__ bucket_fill,
                                               __half* __restrict__ xw1h,
                                               __half* __restrict__ hw2p) {
    int t = threadIdx.x;
    if (blockIdx.x == 5 && t < NB) bucket_fill[t] = 0;
    if (blockIdx.x == 0 && t < 13) {     // zero row NN of both gather tables (dummy target)
        float4 z = make_float4(0.f, 0.f, 0.f, 0.f);
        if (t < 8) ((float4*)(xw1h + (size_t)NN * HID))[t] = z;
        else       ((float4*)(hw2p + (size_t)NN * 40))[t - 8] = z;
    }
    int e = blockIdx.x * 256 + t;
    if (e < 1024) {
        int ct = e >> 8, ki = (e >> 6) & 3, l = e & 63;
        int q = l >> 4, n = l & 15;
        v8h o;
        #pragma unroll
        for (int j = 0; j < 8; ++j)
            o[j] = (_Float16)W1[(ki * 32 + q * 8 + j) * 64 + ct * 16 + n];
        ((v8h*)w1frag)[e] = o;
    } else {
        int e2 = e - 1024;
        if (e2 < 384) {
            int ct = e2 >> 7, ki = (e2 >> 6) & 1, l = e2 & 63;
            int q = l >> 4, n = l & 15;
            int col = ct * 16 + n;
            v8h o;
            #pragma unroll
            for (int j = 0; j < 8; ++j)
                o[j] = (col < DOUT) ? (_Float16)W2[(ki * 32 + q * 8 + j) * DOUT + col]
                                    : (_Float16)0.0f;
            ((v8h*)w2frag)[e2] = o;
        }
    }
}

// ---------------- fat kernel: edge scatter (blocks < S_BLKS) || gemm1 (rest) ----------------
__global__ __launch_bounds__(256) void k_fat(const int* __restrict__ src,
                                             const int* __restrict__ dst,
                                             int* __restrict__ bucket_fill,
                                             int* __restrict__ ebuf,
                                             const float* __restrict__ x,
                                             const __half* __restrict__ w1frag,
                                             __half* __restrict__ xw1h) {
    __shared__ int smem[4096];           // 16 KB union
    int t = threadIdx.x;
    if (blockIdx.x < S_BLKS) {
        int* hist  = smem;
        int* gbase = smem + 256;
        int* rcur  = smem + 512;
        for (int i = t; i < NB; i += 256) { hist[i] = 0; rcur[i] = 0; }
        __syncthreads();
        int e0 = blockIdx.x * CH;
        int ep[16], eb[16];
        #pragma unroll
        for (int j = 0; j < 16; ++j) {
            int e = e0 + j * 256 + t;
            bool valid = (e < EE);
            if (valid) {
                int dd_ = dst[e];
                ep[j] = (src[e] << 9) | (dd_ & 511);
                eb[j] = dd_ >> 9;
                atomicAdd(&hist[eb[j]], 1);
            } else {
                ep[j] = 0; eb[j] = -1;
            }
        }
        __syncthreads();
        for (int i = t; i < NB; i += 256)
            gbase[i] = atomicAdd(&bucket_fill[i], hist[i]);
        __syncthreads();
        #pragma unroll
        for (int j = 0; j < 16; ++j) {
            if (eb[j] >= 0) {
                int r = atomicAdd(&rcur[eb[j]], 1);
                ebuf[eb[j] * SEG + gbase[eb[j]] + r] = ep[j];
            }
        }
    } else {
        float4* sb4 = (float4*)smem;     // 1024 float4 = 16 KB
        const float4* wf = (const float4*)w1frag;
        #pragma unroll
        for (int i = 0; i < 4; ++i) sb4[t + i * 256] = wf[t + i * 256];
        __syncthreads();
        const v8h* sbh = (const v8h*)sb4;
        int wv = t >> 6, l = t & 63;
        int q = l >> 4, n = l & 15;
        int row0 = (blockIdx.x - S_BLKS) * 64 + wv * 16;
        int m = row0 + n;
        bool mv = (m < NN);
        const float* xr = x + (size_t)(mv ? m : 0) * DIN + q * 8;
        v8h afrag[4];
        #pragma unroll
        for (int ki = 0; ki < 4; ++ki) {
            float4 u0 = mv ? ((const float4*)(xr + ki * 32))[0] : make_float4(0.f,0.f,0.f,0.f);
            float4 u1 = mv ? ((const float4*)(xr + ki * 32))[1] : make_float4(0.f,0.f,0.f,0.f);
            v8h a;
            a[0] = (_Float16)u0.x; a[1] = (_Float16)u0.y;
            a[2] = (_Float16)u0.z; a[3] = (_Float16)u0.w;
            a[4] = (_Float16)u1.x; a[5] = (_Float16)u1.y;
            a[6] = (_Float16)u1.z; a[7] = (_Float16)u1.w;
            afrag[ki] = a;
        }
        v4f acc[4];
        #pragma unroll
        for (int ct = 0; ct < 4; ++ct) acc[ct] = (v4f){0.f, 0.f, 0.f, 0.f};
        #pragma unroll
        for (int ct = 0; ct < 4; ++ct) {
            #pragma unroll
            for (int ki = 0; ki < 4; ++ki)
                acc[ct] = __builtin_amdgcn_mfma_f32_16x16x32_f16(
                    afrag[ki], sbh[(ct * 4 + ki) * 64 + l], acc[ct], 0, 0, 0);
        }
        _Float16* outh = (_Float16*)xw1h;
        #pragma unroll
        for (int r = 0; r < 4; ++r) {
            int rr = row0 + q * 4 + r;
            if (rr < NN) {
                #pragma unroll
                for (int ct = 0; ct < 4; ++ct)
                    outh[(size_t)rr * HID + ct * 16 + n] = (_Float16)acc[ct][r];
            }
        }
    }
}

// ---------------- per-bucket CSR (8-padded) + dinv + xw1h scaling (512 threads) ----------------
__global__ __launch_bounds__(512) void kB_csr(const int* __restrict__ ebuf,
                                              const int* __restrict__ bucket_fill,
                                              int* __restrict__ pofs,
                                              float* __restrict__ dinv,
                                              int* __restrict__ esrc,
                                              __half* __restrict__ xw1h) {
    __shared__ int lcnt[BN], sAa[BN], sBb[BN], lcur[BN];
    int t = threadIdx.x;
    int b = blockIdx.x;
    int eb0 = b * SEG;
    int eb2 = b * SEG2;
    int ecnt = bucket_fill[b];
    lcnt[t] = 0;
    __syncthreads();
    for (int j = t; j < ecnt; j += 512)
        atomicAdd(&lcnt[ebuf[eb0 + j] & 511], 1);
    __syncthreads();
    int cnt  = lcnt[t];
    int pcnt = (cnt + 7) & ~7;           // pad each dst's list to a multiple of 8
    sAa[t] = pcnt;
    __syncthreads();
    int* s = sAa; int* d = sBb;
    for (int off = 1; off < BN; off <<= 1) {
        d[t] = s[t] + ((t >= off) ? s[t - off] : 0);
        __syncthreads();
        int* tmp = s; s = d; d = tmp;
    }
    int base_node = b * BN;
    int excl = s[t] - pcnt;              // padded exclusive offset
    lcur[t] = excl;
    int node = base_node + t;
    if (node < NN) {
        pofs[node] = ((eb2 + excl) << 10) | pcnt;     // padded base + padded count
        dinv[node] = rsqrtf((float)cnt + 1.0f);       // +1 self-loop (real count)
    }
    // dummy-fill the whole padded region (slack slots gather the zero row NN)
    for (int i = t; i < SEG2; i += 512) esrc[eb2 + i] = NN;
    __syncthreads();
    for (int j = t; j < ecnt; j += 512) {
        int p = ebuf[eb0 + j];
        int r = atomicAdd(&lcur[p & 511], 1);
        esrc[eb2 + r] = p >> 9;          // plain src id (no sel bits needed)
    }
    // scale this bucket's xw1h rows by dinv (k_fat wrote them unscaled)
    float4* xr4 = (float4*)xw1h;
    for (int i = t; i < BN * 8; i += 512) {
        int li = i >> 3;
        int node2 = base_node + li;
        if (node2 < NN) {
            float di = rsqrtf((float)lcnt[li] + 1.0f);
            float4 v = xr4[(size_t)node2 * 8 + (i & 7)];
            __half2* h = (__half2*)&v;
            #pragma unroll
            for (int u = 0; u < 4; ++u) {
                float2 f = __half22float2(h[u]);
                h[u] = __floats2half2_rn(f.x * di, f.y * di);
            }
            xr4[(size_t)node2 * 8 + (i & 7)] = v;
        }
    }
}

// ---------------- fused: layer-1 aggregation (1 dst/group, max occupancy) + layer-2 GEMM ----------------
// Phase A: 32 groups x 8 lanes; group g owns dst d0+g. Padded-to-8 lists make
// every iteration a full branch-free 8-deep gather burst (no remainder tail).
// Lean register footprint (<=64 VGPR via launch_bounds) -> 8 waves/SIMD: TLP
// hides L2/L3 gather latency instead of per-wave pipelining.
// Phase B: 2 waves x 16 rows; A-frags from LDS halves (+bias+relu), 6 MFMAs;
// epilogue writes PACKED 40-half rows of hw2p, pre-scaled by dinv[row].
__global__ __launch_bounds__(256, 8) void k_fuse(const __half* __restrict__ xw1h,
                                                 const float* __restrict__ dinv,
                                                 const int* __restrict__ pofs,
                                                 const int* __restrict__ esrc,
                                                 const float* __restrict__ b1,
                                                 const __half* __restrict__ w2frag,
                                                 __half* __restrict__ hw2p) {
    __shared__ __half sh[32 * 72];       // 4.5 KB agg rows (stride 144 B, 16B-aligned)
    __shared__ float4 sb4[384];          // 6 KB: W2 B-frags
    __shared__ float sb1[64];
    int t = threadIdx.x;
    const float4* wf = (const float4*)w2frag;
    if (t < 192) { sb4[t] = wf[t]; sb4[t + 192] = wf[t + 192]; }
    if (t >= 192) sb1[t - 192] = b1[t - 192];

    int d0 = blockIdx.x * 32;
    int g = t >> 3, q = t & 7;
    int dd = d0 + g;                     // grid = NN/32 exactly: always < NN
    const float4* tab4 = (const float4*)xw1h;
    float4 tl = make_float4(0.f,0.f,0.f,0.f), th = make_float4(0.f,0.f,0.f,0.f);
    acc8(tab4[(size_t)dd * 8 + q], tl, th);        // self-loop (row pre-scaled)
    int p_ = pofs[dd];
    int j = p_ >> 10;
    int n8 = (p_ & 1023) >> 3;
    for (int m = 0; m < n8; ++m, j += 8) {
        int e[8];
        float4 v[8];
        #pragma unroll
        for (int u = 0; u < 8; ++u) e[u] = esrc[j + u];
        #pragma unroll
        for (int u = 0; u < 8; ++u) v[u] = tab4[(size_t)e[u] * 8 + q];
        #pragma unroll
        for (int u = 0; u < 8; ++u) acc8(v[u], tl, th);
    }
    sthalf8(sh + g * 72 + q * 8, tl, th, dinv[dd]);
    __syncthreads();

    // phase B: waves 0-1, 16 rows each, 6 MFMAs
    int wv = t >> 6, l = t & 63;
    if (wv < 2) {
        const v8h* sbh = (const v8h*)sb4;
        int qq = l >> 4, n = l & 15;
        int srow = wv * 16 + n;
        v8h afrag[2];
        #pragma unroll
        for (int ki = 0; ki < 2; ++ki) {
            v8h a = *(const v8h*)(sh + srow * 72 + ki * 32 + qq * 8);
            #pragma unroll
            for (int jj = 0; jj < 8; ++jj) {
                float av = (float)a[jj] + sb1[ki * 32 + qq * 8 + jj];
                a[jj] = (_Float16)fmaxf(av, 0.f);
            }
            afrag[ki] = a;
        }
        v4f acc[3];
        #pragma unroll
        for (int ct = 0; ct < 3; ++ct) acc[ct] = (v4f){0.f, 0.f, 0.f, 0.f};
        #pragma unroll
        for (int ct = 0; ct < 3; ++ct) {
            #pragma unroll
            for (int ki = 0; ki < 2; ++ki)
                acc[ct] = __builtin_amdgcn_mfma_f32_16x16x32_f16(
                    afrag[ki], sbh[(ct * 2 + ki) * 64 + l], acc[ct], 0, 0, 0);
        }
        // packed 40-half rows, pre-scaled by dinv[row]
        _Float16* outh = (_Float16*)hw2p;
        #pragma unroll
        for (int r = 0; r < 4; ++r) {
            int rr = d0 + wv * 16 + qq * 4 + r;
            float di = dinv[rr];
            outh[(size_t)rr * 40 + n]      = (_Float16)(acc[0][r] * di);
            outh[(size_t)rr * 40 + 16 + n] = (_Float16)(acc[1][r] * di);
            if (n < 8)
                outh[(size_t)rr * 40 + 32 + n] = (_Float16)(acc[2][r] * di);
        }
    }
}

// ---------------- layer 2 aggregation: 1 dst/group, packed 80B rows, no LDS, max occupancy ----------------
__global__ __launch_bounds__(256, 8) void k_agg2(const __half* __restrict__ hw2p,
                                                 const float* __restrict__ dinv,
                                                 const int* __restrict__ pofs,
                                                 const int* __restrict__ esrc,
                                                 const float* __restrict__ b2,
                                                 float* __restrict__ out) {
    int t = threadIdx.x;
    int g = t >> 3, q = t & 7;
    int qc = (q < 5) ? q : (q - 3);      // lanes 5-7 duplicate granules 2-4 (coalescer merges)
    int dd = blockIdx.x * 32 + g;        // grid = NN/32 exactly
    const float4* tab4 = (const float4*)hw2p;
    float4 tl = make_float4(0.f,0.f,0.f,0.f), th = make_float4(0.f,0.f,0.f,0.f);
    acc8(tab4[(size_t)dd * 5 + qc], tl, th);       // self-loop (pre-scaled)
    int p_ = pofs[dd];
    int j = p_ >> 10;
    int n8 = (p_ & 1023) >> 3;
    for (int m = 0; m < n8; ++m, j += 8) {
        int e[8];
        float4 v[8];
        #pragma unroll
        for (int u = 0; u < 8; ++u) e[u] = esrc[j + u];
        #pragma unroll
        for (int u = 0; u < 8; ++u) v[u] = tab4[(size_t)e[u] * 5 + qc];
        #pragma unroll
        for (int u = 0; u < 8; ++u) acc8(v[u], tl, th);
    }
    if (q < 5) {                         // channels q*8 .. q*8+7 (40 total)
        float di = dinv[dd];
        const float4* b24 = (const float4*)(b2 + q * 8);
        float4 c0 = b24[0], c1 = b24[1];
        float* op = out + (size_t)dd * DOUT + q * 8;
        ((float4*)op)[0] = make_float4(tl.x * di + c0.x, tl.y * di + c0.y,
                                       tl.z * di + c0.z, tl.w * di + c0.w);
        ((float4*)op)[1] = make_float4(th.x * di + c1.x, th.y * di + c1.y,
                                       th.z * di + c1.z, th.w * di + c1.w);
    }
}

extern "C" void kernel_launch(void* const* d_in, const int* in_sizes, int n_in,
                              void* d_out, int out_size, void* d_ws, size_t ws_size,
                              hipStream_t stream) {
    const float* x  = (const float*)d_in[0];
    const float* W1 = (const float*)d_in[1];
    const float* b1 = (const float*)d_in[2];
    const float* W2 = (const float*)d_in[3];
    const float* b2 = (const float*)d_in[4];
    const int*   ei = (const int*)d_in[5];
    const int* src = ei;        // edge_index[0]
    const int* dst = ei + EE;   // edge_index[1]
    float* out = (float*)d_out;

    float* ws = (float*)d_ws;
    int*    bucket_fill = (int*)ws;                     // [0,256)
    int*    pofs        = (int*)ws + 256;               // NN
    float*  dinv        = ws + 100352;                  // NN
    int*    ebuf        = (int*)ws + 200704;            // NB*SEG  = 1,605,632
    int*    esrc        = (int*)ws + 1806336;           // NB*SEG2 = 2,007,040
    __half* xw1h        = (__half*)(ws + 3813376);      // (NN+1)*64 halves (pre-scaled; row NN = 0)
    __half* hw2p        = (__half*)(ws + 7013408);      // (NN+1)*40 halves (packed, pre-scaled; row NN = 0)
    __half* w1frag      = (__half*)(ws + 9013428);      // 8192 halves
    __half* w2frag      = (__half*)(ws + 9017524);      // 3072 halves
    // total: 9,019,060 floats = 36.1 MB

    k_wprep <<<6, 256, 0, stream>>>(W1, W2, w1frag, w2frag, bucket_fill, xw1h, hw2p);
    k_fat   <<<S_BLKS + G_BLKS, 256, 0, stream>>>(src, dst, bucket_fill, ebuf, x, w1frag, xw1h);
    kB_csr  <<<NB, 512, 0, stream>>>(ebuf, bucket_fill, pofs, dinv, esrc, xw1h);
    k_fuse  <<<NN / 32, 256, 0, stream>>>(xw1h, dinv, pofs, esrc, b1, w2frag, hw2p);
    k_agg2  <<<NN / 32, 256, 0, stream>>>(hw2p, dinv, pofs, esrc, b2, out);
}